// Round 11
// baseline (185.313 us; speedup 1.0000x reference)
//
#include <hip/hip_runtime.h>
#include <hip/hip_bf16.h>
#include <math.h>

// Problem constants (B=1)
#define HH 16
#define WW 16
#define DD 16
#define LL 4096          // H*W*Dd
#define CC 48            // d_model
#define DIN 48           // d_inner
#define NN 16            // d_state
#define RR 3             // dt_rank
#define KK 8             // scan directions
#define KD 384           // K*DIN
#define NCH 64           // chunks along L
#define CHL 64           // chunk length

// DPP-based 16-lane sum (quad_perm xor1/xor2 + row_ror:4/8). Pure VALU.
__device__ __forceinline__ float dpp_add(float x, const int ctrl_tag) {
    int xi = __float_as_int(x);
    int yi;
    switch (ctrl_tag) {
        case 0: yi = __builtin_amdgcn_update_dpp(0, xi, 0xB1, 0xF, 0xF, true); break; // quad_perm [1,0,3,2]
        case 1: yi = __builtin_amdgcn_update_dpp(0, xi, 0x4E, 0xF, 0xF, true); break; // quad_perm [2,3,0,1]
        case 2: yi = __builtin_amdgcn_update_dpp(0, xi, 0x124, 0xF, 0xF, true); break; // row_ror:4
        default: yi = __builtin_amdgcn_update_dpp(0, xi, 0x128, 0xF, 0xF, true); break; // row_ror:8
    }
    return x + __int_as_float(yi);
}
__device__ __forceinline__ float row16_sum(float p) {
    p = dpp_add(p, 0);
    p = dpp_add(p, 1);
    p = dpp_add(p, 2);
    p = dpp_add(p, 3);
    return p;
}

__device__ __forceinline__ int perm_src(int kperm, int ll) {
    int a = ll >> 8, b2 = (ll >> 4) & 15, c2 = ll & 15;
    switch (kperm) {
        case 0: return ll;                       // (h,w,dd)
        case 1: return b2 * 256 + a * 16 + c2;   // swap h,w
        case 2: return c2 * 256 + b2 * 16 + a;   // swap h,dd
        default: return a * 256 + c2 * 16 + b2;  // swap w,dd
    }
}

// Shared front end for the two scan kernels: gather u tile (permuted),
// x_proj GEMM into xd, delta = softplus(dt_proj) into dt. All in LDS.
__device__ __forceinline__ void build_tiles(const float* __restrict__ xc,
                                            const float* __restrict__ xpw,
                                            const float* __restrict__ dtw,
                                            const float* __restrict__ dtb,
                                            int k, int l0, int kperm, int krev,
                                            int tid,
                                            float* xt, float* xd, float* dt) {
#pragma unroll
    for (int r = 0; r < 4; ++r) {
        int item = r * 768 + tid;                      // 3072 = 48 d * 64 i
        int d = item >> 6, i = item & 63;
        int lg = l0 + i;
        int ll = krev ? (LL - 1 - lg) : lg;
        xt[d * 68 + i] = xc[d * LL + perm_src(kperm, ll)];
    }
    __syncthreads();
    if (tid < 560) {                                   // 35 c x 16 l4
        int cc = tid % 35, l4 = tid / 35;
        const float* wr = xpw + (k * 35 + cc) * DIN;
        float4 acc = {0.f, 0.f, 0.f, 0.f};
#pragma unroll
        for (int d2 = 0; d2 < 48; ++d2) {
            float4 v = ((const float4*)(xt + d2 * 68))[l4];
            float w = wr[d2];
            acc.x += v.x * w; acc.y += v.y * w; acc.z += v.z * w; acc.w += v.w * w;
        }
        float* o = xd + cc * 65 + l4 * 4;
        o[0] = acc.x; o[1] = acc.y; o[2] = acc.z; o[3] = acc.w;
    }
    __syncthreads();
#pragma unroll
    for (int r = 0; r < 4; ++r) {
        int item = r * 768 + tid;                      // 3072 = 48 d * 64 l
        int d2 = item >> 6, l = item & 63;
        int gd = k * DIN + d2;
        float v = xd[l] * dtw[gd * 3] + xd[65 + l] * dtw[gd * 3 + 1]
                + xd[130 + l] * dtw[gd * 3 + 2] + dtb[gd];
        dt[d2 * 68 + l] = (v > 20.f) ? v : log1pf(__expf(v));
    }
    __syncthreads();
}

// ---- Kernel 1 (k_front): fused in_proj + depthwise conv + SiLU + z. --------
// Blocks 0..47: channel d — xm[d][:] lives only in LDS; conv reads LDS.
// Blocks 48..79: z tile (128 l x 48 e), coalesced 192B row writes.
__global__ __launch_bounds__(256) void k_front(const float* __restrict__ x,
                                               const float* __restrict__ ipw,
                                               const float* __restrict__ cw,
                                               const float* __restrict__ cb,
                                               float* __restrict__ xc,
                                               float* __restrict__ z) {
    int bid = blockIdx.x, tid = threadIdx.x;
    if (bid < DIN) {
        int d = bid;
        __shared__ float xm_l[LL];
        // preload this channel's in_proj row into registers
        const float4* wr4 = (const float4*)(ipw + d * CC);
        float4 wreg[12];
#pragma unroll
        for (int i = 0; i < 12; ++i) wreg[i] = wr4[i];
#pragma unroll
        for (int r = 0; r < 16; ++r) {
            int l = r * 256 + tid;
            const float4* xr = (const float4*)(x + l * CC);
            float acc = 0.f;
#pragma unroll
            for (int c4 = 0; c4 < 12; ++c4) {
                float4 a = xr[c4], b = wreg[c4];
                acc += a.x * b.x + a.y * b.y + a.z * b.z + a.w * b.w;
            }
            xm_l[l] = acc;
        }
        __syncthreads();
        const float* wp = cw + d * 27;
        float cbd = cb[d];
#pragma unroll
        for (int r = 0; r < 16; ++r) {
            int s = r * 256 + tid;
            int dd = s & 15, w = (s >> 4) & 15, h = s >> 8;
            float acc = 0.f;
#pragma unroll
            for (int i = -1; i <= 1; ++i) {
                int hh = h + i; if (hh < 0 || hh > 15) continue;
#pragma unroll
                for (int j = -1; j <= 1; ++j) {
                    int ww2 = w + j; if (ww2 < 0 || ww2 > 15) continue;
#pragma unroll
                    for (int q = -1; q <= 1; ++q) {
                        int dd2 = dd + q; if (dd2 < 0 || dd2 > 15) continue;
                        acc += wp[(i + 1) * 9 + (j + 1) * 3 + (q + 1)]
                             * xm_l[hh * 256 + ww2 * 16 + dd2];
                    }
                }
            }
            acc += cbd;
            xc[d * LL + s] = acc / (1.f + __expf(-acc));  // SiLU
        }
    } else {
        // z tile: 128 l x 48 e, item-major (consecutive tid -> consecutive e)
        int lb = (bid - DIN) * 128;
#pragma unroll
        for (int r = 0; r < 24; ++r) {
            int item = r * 256 + tid;                  // 0..6143
            int l = lb + item / 48, e = item % 48;
            const float4* xr = (const float4*)(x + l * CC);
            const float4* wr = (const float4*)(ipw + (DIN + e) * CC);
            float acc = 0.f;
#pragma unroll
            for (int c4 = 0; c4 < 12; ++c4) {
                float4 a = xr[c4], b = wr[c4];
                acc += a.x * b.x + a.y * b.y + a.z * b.z + a.w * b.w;
            }
            z[l * DIN + e] = acc;
        }
    }
}

// ---- Kernel 2 (k_scanA): tiles + scan phase 1 -> chunk summaries. ----------
// Summary layout [c][k][tid]: scan2/scanB accesses are coalesced.
__global__ __launch_bounds__(768) void k_scanA(const float* __restrict__ xc,
                                               const float* __restrict__ xpw,
                                               const float* __restrict__ dtw,
                                               const float* __restrict__ dtb,
                                               const float* __restrict__ A_logs,
                                               float* __restrict__ pa_g,
                                               float* __restrict__ hf_g) {
    int k = blockIdx.x >> 6;
    int c = blockIdx.x & (NCH - 1);
    int l0 = c * CHL;
    int tid = threadIdx.x;
    __shared__ float xt[48 * 68];
    __shared__ float xd[35 * 65];
    __shared__ float dt[48 * 68];
    build_tiles(xc, xpw, dtw, dtb, k, l0, k & 3, k & 4, tid, xt, xd, dt);
    int d = tid >> 4, n = tid & 15;
    int gid = k * DIN + d;
    float A = -__expf(A_logs[gid * NN + n]);
    float h = 0.f, pa = 1.f;
#pragma unroll 8
    for (int i = 0; i < CHL; ++i) {
        float delta = dt[d * 68 + i];
        float u = xt[d * 68 + i];
        float Bv = xd[(3 + n) * 65 + i];
        float dA = __expf(delta * A);
        h = h * dA + delta * u * Bv;
        pa *= dA;
    }
    size_t si = ((size_t)c * KK + k) * 768 + tid;
    pa_g[si] = pa;
    hf_g[si] = h;
}

// ---- Kernel 3 (k_scan2): serial combine over 64 chunk summaries. -----------
// Thread p = k*768 + tid768; loop over c reads/writes coalesced slabs.
__global__ __launch_bounds__(256) void k_scan2(const float* __restrict__ pa_g,
                                               const float* __restrict__ hf_g,
                                               float* __restrict__ h0_g) {
    int t = blockIdx.x * 256 + threadIdx.x;            // 0..6143
    if (t >= KK * 768) return;
    int k = t / 768;
    int tid768 = t - k * 768;
    float h = 0.f;
#pragma unroll 4
    for (int c = 0; c < NCH; ++c) {
        size_t idx = ((size_t)c * KK + k) * 768 + tid768;
        h0_g[idx] = h;
        h = pa_g[idx] * h + hf_g[idx];
    }
}

// ---- Kernel 4 (k_scanB): tiles again + h0 seed + phase 3 + y2 store. -------
__global__ __launch_bounds__(768) void k_scanB(const float* __restrict__ xc,
                                               const float* __restrict__ xpw,
                                               const float* __restrict__ dtw,
                                               const float* __restrict__ dtb,
                                               const float* __restrict__ A_logs,
                                               const float* __restrict__ Ds,
                                               const float* __restrict__ h0_g,
                                               float* __restrict__ y2) {
    int k = blockIdx.x >> 6;
    int c = blockIdx.x & (NCH - 1);
    int l0 = c * CHL;
    int tid = threadIdx.x;
    int kperm = k & 3, krev = k & 4;
    __shared__ float xt[48 * 68];
    __shared__ float xd[35 * 65];
    __shared__ float dt[48 * 68];
    __shared__ float y_t[48 * 68];
    build_tiles(xc, xpw, dtw, dtb, k, l0, kperm, krev, tid, xt, xd, dt);
    float h = h0_g[((size_t)c * KK + k) * 768 + tid];  // one coalesced load
    int d = tid >> 4, n = tid & 15;
    int gid = k * DIN + d;
    float A = -__expf(A_logs[gid * NN + n]);
    float Dv = Ds[gid];
#pragma unroll 8
    for (int i = 0; i < CHL; ++i) {
        float delta = dt[d * 68 + i];
        float u = xt[d * 68 + i];
        float Bv = xd[(3 + n) * 65 + i];
        float Cv = xd[(19 + n) * 65 + i];
        float dA = __expf(delta * A);
        h = h * dA + delta * u * Bv;
        float p = row16_sum(h * Cv);
        if (n == 0) y_t[d * 68 + i] = p + Dv * u;
    }
    __syncthreads();
    // de-permuted store: y2[s][k*48..+47], 192B contiguous
    {
        int g = tid >> 6, l = tid & 63;                // g: 0..11
        int lg = l0 + l;
        int ll = krev ? (LL - 1 - lg) : lg;
        int s = perm_src(kperm, ll);
        float4 v;
#pragma unroll
        for (int j = 0; j < 4; ++j) (&v.x)[j] = y_t[(g * 4 + j) * 68 + l];
        ((float4*)(y2 + (size_t)s * KD + k * DIN))[g] = v;
    }
}

// ---- Kernel 5: sum dirs + LayerNorm + gate + out_proj. Wave per s. ---------
__global__ __launch_bounds__(256) void k_final2(const float* __restrict__ y2,
                                                const float* __restrict__ z,
                                                const float* __restrict__ nw,
                                                const float* __restrict__ nb,
                                                const float* __restrict__ opw,
                                                float* __restrict__ out) {
    int wv = threadIdx.x >> 6, lane = threadIdx.x & 63;
    int s = blockIdx.x * 4 + wv;
    __shared__ float g[4][DIN];
    float val = 0.f;
    if (lane < DIN) {
        const float* yp = y2 + (size_t)s * KD + lane;
#pragma unroll
        for (int k = 0; k < KK; ++k) val += yp[k * DIN];
    }
    float m = val;
#pragma unroll
    for (int o = 32; o >= 1; o >>= 1) m += __shfl_xor(m, o, 64);
    m *= (1.f / 48.f);
    float dv = (lane < DIN) ? (val - m) : 0.f;
    float v2 = dv * dv;
#pragma unroll
    for (int o = 32; o >= 1; o >>= 1) v2 += __shfl_xor(v2, o, 64);
    v2 *= (1.f / 48.f);
    float inv = rsqrtf(v2 + 1e-5f);
    if (lane < DIN) {
        float yn = dv * inv * nw[lane] + nb[lane];
        float zz = z[s * DIN + lane];
        g[wv][lane] = yn * (zz / (1.f + __expf(-zz)));
    }
    __syncthreads();
    if (lane < DIN) {
        const float* wr = opw + lane * DIN;            // out_proj_w[c, e]
        float acc = 0.f;
#pragma unroll
        for (int e = 0; e < DIN; ++e) acc += g[wv][e] * wr[e];
        out[s * CC + lane] = acc;
    }
}

extern "C" void kernel_launch(void* const* d_in, const int* in_sizes, int n_in,
                              void* d_out, int out_size, void* d_ws, size_t ws_size,
                              hipStream_t stream) {
    const float* x      = (const float*)d_in[0];
    const float* ipw    = (const float*)d_in[1];
    const float* cw     = (const float*)d_in[2];
    const float* cb     = (const float*)d_in[3];
    const float* xpw    = (const float*)d_in[4];
    const float* dtw    = (const float*)d_in[5];
    const float* dtb    = (const float*)d_in[6];
    const float* A_logs = (const float*)d_in[7];
    const float* Ds     = (const float*)d_in[8];
    const float* nw     = (const float*)d_in[9];
    const float* nb     = (const float*)d_in[10];
    const float* opw    = (const float*)d_in[11];
    float* out = (float*)d_out;

    float* ws   = (float*)d_ws;
    float* xc   = ws;                                  // DIN*LL
    float* z    = xc + DIN * LL;                       // LL*DIN
    float* y2   = z + LL * DIN;                        // LL*KD
    float* pa_g = y2 + (size_t)LL * KD;                // NCH*KK*768
    float* hf_g = pa_g + (size_t)NCH * KK * 768;
    float* h0_g = hf_g + (size_t)NCH * KK * 768;

    k_front<<<DIN + 32, 256, 0, stream>>>(x, ipw, cw, cb, xc, z);
    k_scanA<<<KK * NCH, 768, 0, stream>>>(xc, xpw, dtw, dtb, A_logs, pa_g, hf_g);
    k_scan2<<<(KK * 768 + 255) / 256, 256, 0, stream>>>(pa_g, hf_g, h0_g);
    k_scanB<<<KK * NCH, 768, 0, stream>>>(xc, xpw, dtw, dtb, A_logs, Ds,
                                          h0_g, y2);
    k_final2<<<LL / 4, 256, 0, stream>>>(y2, z, nw, nb, opw, out);
}

// Round 12
// 158.026 us; speedup vs baseline: 1.1727x; 1.1727x over previous
//
#include <hip/hip_runtime.h>
#include <hip/hip_bf16.h>
#include <math.h>

// Problem constants (B=1)
#define HH 16
#define WW 16
#define DD 16
#define LL 4096          // H*W*Dd
#define CC 48            // d_model
#define DIN 48           // d_inner
#define NN 16            // d_state
#define RR 3             // dt_rank
#define KK 8             // scan directions
#define KD 384           // K*DIN
#define NCH 64           // chunks along L
#define CHL 64           // chunk length

// DPP-based 16-lane sum (quad_perm xor1/xor2 + row_ror:4/8). Pure VALU.
__device__ __forceinline__ float dpp_add(float x, const int ctrl_tag) {
    int xi = __float_as_int(x);
    int yi;
    switch (ctrl_tag) {
        case 0: yi = __builtin_amdgcn_update_dpp(0, xi, 0xB1, 0xF, 0xF, true); break; // quad_perm [1,0,3,2]
        case 1: yi = __builtin_amdgcn_update_dpp(0, xi, 0x4E, 0xF, 0xF, true); break; // quad_perm [2,3,0,1]
        case 2: yi = __builtin_amdgcn_update_dpp(0, xi, 0x124, 0xF, 0xF, true); break; // row_ror:4
        default: yi = __builtin_amdgcn_update_dpp(0, xi, 0x128, 0xF, 0xF, true); break; // row_ror:8
    }
    return x + __int_as_float(yi);
}
__device__ __forceinline__ float row16_sum(float p) {
    p = dpp_add(p, 0);
    p = dpp_add(p, 1);
    p = dpp_add(p, 2);
    p = dpp_add(p, 3);
    return p;
}

__device__ __forceinline__ int perm_src(int kperm, int ll) {
    int a = ll >> 8, b2 = (ll >> 4) & 15, c2 = ll & 15;
    switch (kperm) {
        case 0: return ll;                       // (h,w,dd)
        case 1: return b2 * 256 + a * 16 + c2;   // swap h,w
        case 2: return c2 * 256 + b2 * 16 + a;   // swap h,dd
        default: return a * 256 + c2 * 16 + b2;  // swap w,dd
    }
}

// Shared front end for the two scan kernels: gather u tile (permuted),
// x_proj GEMM into xd, delta = softplus(dt_proj) into dt. All in LDS.
__device__ __forceinline__ void build_tiles(const float* __restrict__ xc,
                                            const float* __restrict__ xpw,
                                            const float* __restrict__ dtw,
                                            const float* __restrict__ dtb,
                                            int k, int l0, int kperm, int krev,
                                            int tid,
                                            float* xt, float* xd, float* dt) {
#pragma unroll
    for (int r = 0; r < 4; ++r) {
        int item = r * 768 + tid;                      // 3072 = 48 d * 64 i
        int d = item >> 6, i = item & 63;
        int lg = l0 + i;
        int ll = krev ? (LL - 1 - lg) : lg;
        xt[d * 68 + i] = xc[d * LL + perm_src(kperm, ll)];
    }
    __syncthreads();
    if (tid < 560) {                                   // 35 c x 16 l4
        int cc = tid % 35, l4 = tid / 35;
        const float* wr = xpw + (k * 35 + cc) * DIN;
        float4 acc = {0.f, 0.f, 0.f, 0.f};
#pragma unroll
        for (int d2 = 0; d2 < 48; ++d2) {
            float4 v = ((const float4*)(xt + d2 * 68))[l4];
            float w = wr[d2];
            acc.x += v.x * w; acc.y += v.y * w; acc.z += v.z * w; acc.w += v.w * w;
        }
        float* o = xd + cc * 65 + l4 * 4;
        o[0] = acc.x; o[1] = acc.y; o[2] = acc.z; o[3] = acc.w;
    }
    __syncthreads();
#pragma unroll
    for (int r = 0; r < 4; ++r) {
        int item = r * 768 + tid;                      // 3072 = 48 d * 64 l
        int d2 = item >> 6, l = item & 63;
        int gd = k * DIN + d2;
        float v = xd[l] * dtw[gd * 3] + xd[65 + l] * dtw[gd * 3 + 1]
                + xd[130 + l] * dtw[gd * 3 + 2] + dtb[gd];
        dt[d2 * 68 + l] = (v > 20.f) ? v : log1pf(__expf(v));
    }
    __syncthreads();
}

// ---------------- Kernel 1: in_proj (wide-parallel, proven R7) --------------
__global__ __launch_bounds__(256) void k_inproj(const float* __restrict__ x,
                                                const float* __restrict__ W,
                                                float* __restrict__ xm,
                                                float* __restrict__ z) {
    int tid = blockIdx.x * 256 + threadIdx.x;          // l*96 + e
    if (tid >= LL * 96) return;
    int e = tid % 96, l = tid / 96;
    const float4* xr = (const float4*)(x + l * CC);
    const float4* wr = (const float4*)(W + e * CC);
    float acc = 0.f;
#pragma unroll
    for (int c4 = 0; c4 < CC / 4; ++c4) {
        float4 a = xr[c4], b = wr[c4];
        acc += a.x * b.x + a.y * b.y + a.z * b.z + a.w * b.w;
    }
    if (e < DIN) xm[e * LL + l] = acc;
    else         z[l * DIN + (e - DIN)] = acc;
}

// ---------------- Kernel 2: depthwise conv + SiLU (proven R7) ---------------
__global__ __launch_bounds__(256) void k_conv(const float* __restrict__ xm,
                                              const float* __restrict__ cw,
                                              const float* __restrict__ cb,
                                              float* __restrict__ xc) {
    int tid = blockIdx.x * 256 + threadIdx.x;          // d*LL + s
    if (tid >= DIN * LL) return;
    int s = tid & (LL - 1), d = tid >> 12;
    int dd = s & 15, w = (s >> 4) & 15, h = s >> 8;
    const float* wp = cw + d * 27;
    const float* xp = xm + d * LL;
    float acc = 0.f;
#pragma unroll
    for (int i = -1; i <= 1; ++i) {
        int hh = h + i; if (hh < 0 || hh > 15) continue;
#pragma unroll
        for (int j = -1; j <= 1; ++j) {
            int ww2 = w + j; if (ww2 < 0 || ww2 > 15) continue;
#pragma unroll
            for (int q = -1; q <= 1; ++q) {
                int dd2 = dd + q; if (dd2 < 0 || dd2 > 15) continue;
                acc += wp[(i + 1) * 9 + (j + 1) * 3 + (q + 1)]
                     * xp[hh * 256 + ww2 * 16 + dd2];
            }
        }
    }
    acc += cb[d];
    xc[tid] = acc / (1.f + __expf(-acc));
}

// ---- Kernel 3 (k_scanA): tiles + scan phase 1 -> chunk summaries. ----------
// Summary layout [c][k][tid]: scan2/scanB accesses are coalesced.
__global__ __launch_bounds__(768) void k_scanA(const float* __restrict__ xc,
                                               const float* __restrict__ xpw,
                                               const float* __restrict__ dtw,
                                               const float* __restrict__ dtb,
                                               const float* __restrict__ A_logs,
                                               float* __restrict__ pa_g,
                                               float* __restrict__ hf_g) {
    int k = blockIdx.x >> 6;
    int c = blockIdx.x & (NCH - 1);
    int l0 = c * CHL;
    int tid = threadIdx.x;
    __shared__ float xt[48 * 68];
    __shared__ float xd[35 * 65];
    __shared__ float dt[48 * 68];
    build_tiles(xc, xpw, dtw, dtb, k, l0, k & 3, k & 4, tid, xt, xd, dt);
    int d = tid >> 4, n = tid & 15;
    int gid = k * DIN + d;
    float A = -__expf(A_logs[gid * NN + n]);
    float h = 0.f, pa = 1.f;
#pragma unroll 8
    for (int i = 0; i < CHL; ++i) {
        float delta = dt[d * 68 + i];
        float u = xt[d * 68 + i];
        float Bv = xd[(3 + n) * 65 + i];
        float dA = __expf(delta * A);
        h = h * dA + delta * u * Bv;
        pa *= dA;
    }
    size_t si = ((size_t)c * KK + k) * 768 + tid;
    pa_g[si] = pa;
    hf_g[si] = h;
}

// ---- Kernel 4 (k_scan2): serial combine over 64 chunk summaries. -----------
__global__ __launch_bounds__(256) void k_scan2(const float* __restrict__ pa_g,
                                               const float* __restrict__ hf_g,
                                               float* __restrict__ h0_g) {
    int t = blockIdx.x * 256 + threadIdx.x;            // 0..6143
    if (t >= KK * 768) return;
    int k = t / 768;
    int tid768 = t - k * 768;
    float h = 0.f;
#pragma unroll 4
    for (int c = 0; c < NCH; ++c) {
        size_t idx = ((size_t)c * KK + k) * 768 + tid768;
        h0_g[idx] = h;
        h = pa_g[idx] * h + hf_g[idx];
    }
}

// ---- Kernel 5 (k_scanB): tiles again + h0 seed + phase 3 + y2 store. -------
__global__ __launch_bounds__(768) void k_scanB(const float* __restrict__ xc,
                                               const float* __restrict__ xpw,
                                               const float* __restrict__ dtw,
                                               const float* __restrict__ dtb,
                                               const float* __restrict__ A_logs,
                                               const float* __restrict__ Ds,
                                               const float* __restrict__ h0_g,
                                               float* __restrict__ y2) {
    int k = blockIdx.x >> 6;
    int c = blockIdx.x & (NCH - 1);
    int l0 = c * CHL;
    int tid = threadIdx.x;
    int kperm = k & 3, krev = k & 4;
    __shared__ float xt[48 * 68];
    __shared__ float xd[35 * 65];
    __shared__ float dt[48 * 68];
    __shared__ float y_t[48 * 68];
    build_tiles(xc, xpw, dtw, dtb, k, l0, kperm, krev, tid, xt, xd, dt);
    float h = h0_g[((size_t)c * KK + k) * 768 + tid];  // one coalesced load
    int d = tid >> 4, n = tid & 15;
    int gid = k * DIN + d;
    float A = -__expf(A_logs[gid * NN + n]);
    float Dv = Ds[gid];
#pragma unroll 8
    for (int i = 0; i < CHL; ++i) {
        float delta = dt[d * 68 + i];
        float u = xt[d * 68 + i];
        float Bv = xd[(3 + n) * 65 + i];
        float Cv = xd[(19 + n) * 65 + i];
        float dA = __expf(delta * A);
        h = h * dA + delta * u * Bv;
        float p = row16_sum(h * Cv);
        if (n == 0) y_t[d * 68 + i] = p + Dv * u;
    }
    __syncthreads();
    // de-permuted store: y2[s][k*48..+47], 192B contiguous
    {
        int g = tid >> 6, l = tid & 63;                // g: 0..11
        int lg = l0 + l;
        int ll = krev ? (LL - 1 - lg) : lg;
        int s = perm_src(kperm, ll);
        float4 v;
#pragma unroll
        for (int j = 0; j < 4; ++j) (&v.x)[j] = y_t[(g * 4 + j) * 68 + l];
        ((float4*)(y2 + (size_t)s * KD + k * DIN))[g] = v;
    }
}

// ---- Kernel 6: sum dirs + LayerNorm + gate + out_proj. Wave per s. ---------
__global__ __launch_bounds__(256) void k_final2(const float* __restrict__ y2,
                                                const float* __restrict__ z,
                                                const float* __restrict__ nw,
                                                const float* __restrict__ nb,
                                                const float* __restrict__ opw,
                                                float* __restrict__ out) {
    int wv = threadIdx.x >> 6, lane = threadIdx.x & 63;
    int s = blockIdx.x * 4 + wv;
    __shared__ float g[4][DIN];
    float val = 0.f;
    if (lane < DIN) {
        const float* yp = y2 + (size_t)s * KD + lane;
#pragma unroll
        for (int k = 0; k < KK; ++k) val += yp[k * DIN];
    }
    float m = val;
#pragma unroll
    for (int o = 32; o >= 1; o >>= 1) m += __shfl_xor(m, o, 64);
    m *= (1.f / 48.f);
    float dv = (lane < DIN) ? (val - m) : 0.f;
    float v2 = dv * dv;
#pragma unroll
    for (int o = 32; o >= 1; o >>= 1) v2 += __shfl_xor(v2, o, 64);
    v2 *= (1.f / 48.f);
    float inv = rsqrtf(v2 + 1e-5f);
    if (lane < DIN) {
        float yn = dv * inv * nw[lane] + nb[lane];
        float zz = z[s * DIN + lane];
        g[wv][lane] = yn * (zz / (1.f + __expf(-zz)));
    }
    __syncthreads();
    if (lane < DIN) {
        const float* wr = opw + lane * DIN;            // out_proj_w[c, e]
        float acc = 0.f;
#pragma unroll
        for (int e = 0; e < DIN; ++e) acc += g[wv][e] * wr[e];
        out[s * CC + lane] = acc;
    }
}

extern "C" void kernel_launch(void* const* d_in, const int* in_sizes, int n_in,
                              void* d_out, int out_size, void* d_ws, size_t ws_size,
                              hipStream_t stream) {
    const float* x      = (const float*)d_in[0];
    const float* ipw    = (const float*)d_in[1];
    const float* cw     = (const float*)d_in[2];
    const float* cb     = (const float*)d_in[3];
    const float* xpw    = (const float*)d_in[4];
    const float* dtw    = (const float*)d_in[5];
    const float* dtb    = (const float*)d_in[6];
    const float* A_logs = (const float*)d_in[7];
    const float* Ds     = (const float*)d_in[8];
    const float* nw     = (const float*)d_in[9];
    const float* nb     = (const float*)d_in[10];
    const float* opw    = (const float*)d_in[11];
    float* out = (float*)d_out;

    float* ws   = (float*)d_ws;
    float* xm   = ws;                                  // DIN*LL
    float* z    = xm + DIN * LL;                       // LL*DIN
    float* xc   = z + LL * DIN;                        // DIN*LL
    float* y2   = xc + DIN * LL;                       // LL*KD
    float* pa_g = y2 + (size_t)LL * KD;                // NCH*KK*768
    float* hf_g = pa_g + (size_t)NCH * KK * 768;
    float* h0_g = hf_g + (size_t)NCH * KK * 768;

    k_inproj<<<(LL * 96 + 255) / 256, 256, 0, stream>>>(x, ipw, xm, z);
    k_conv<<<(DIN * LL + 255) / 256, 256, 0, stream>>>(xm, cw, cb, xc);
    k_scanA<<<KK * NCH, 768, 0, stream>>>(xc, xpw, dtw, dtb, A_logs, pa_g, hf_g);
    k_scan2<<<(KK * 768 + 255) / 256, 256, 0, stream>>>(pa_g, hf_g, h0_g);
    k_scanB<<<KK * NCH, 768, 0, stream>>>(xc, xpw, dtw, dtb, A_logs, Ds,
                                          h0_g, y2);
    k_final2<<<LL / 4, 256, 0, stream>>>(y2, z, nw, nb, opw, out);
}